// Round 2
// baseline (1427.076 us; speedup 1.0000x reference)
//
#include <hip/hip_runtime.h>

#define U_ 256
#define B_ 8
#define L_ 16
#define F_ 33
#define S_ 32
#define M_ 64
#define O_ 8
#define SLOTS 44
#define NT 512
#define LOG2E 1.44269504088896340736f
#define EPSF 1e-8f

// d_ws layout (floats from base):
//   A   [SLOTS*NT] : -sigma*log2e        (slot-major: A[e*NT + t])
//   Bm  [SLOTS*NT] : mu*sigma*log2e
//   C   [SLOTS*NT] : softplus(w)*erev    (0 => padding slot)
//   I8  uint8[NT*SLOTS] : presynaptic index i, layout [t][slot]
//   meta uint32[NT] : jA | jB<<8 | bpos<<16

__global__ __launch_bounds__(NT) void lnn_prep(
    const float* __restrict__ w, const float* __restrict__ mu,
    const float* __restrict__ sigma, const float* __restrict__ erev,
    const float* __restrict__ mask, float* __restrict__ ws)
{
    __shared__ int cntLo[U_], cntHi[U_], cnt[U_];
    __shared__ int sortedv[U_];
    __shared__ int pairLp[128];

    const int tid = threadIdx.x;
    float* A  = ws;
    float* Bm = ws + SLOTS * NT;
    float* C  = ws + 2 * SLOTS * NT;
    unsigned char* I8 = (unsigned char*)(ws + 3 * SLOTS * NT);
    unsigned* meta = (unsigned*)(I8 + NT * SLOTS);

    // zero param region (ws is poisoned 0xAA before every launch)
    for (int k = tid; k < 3 * SLOTS * NT; k += NT) ws[k] = 0.0f;
    for (int k = tid; k < NT * SLOTS / 4; k += NT) ((unsigned*)I8)[k] = 0u;

    // half-column nonzero counts
    {
        int j = tid & 255;
        int hi = tid >> 8;
        int c = 0;
        for (int i = hi * 128; i < hi * 128 + 128; ++i)
            c += (mask[i * U_ + j] != 0.0f) ? 1 : 0;
        if (hi == 0) cntLo[j] = c; else cntHi[j] = c;
    }
    __syncthreads();
    if (tid < U_) cnt[tid] = cntLo[tid] + cntHi[tid];
    __syncthreads();
    // rank-sort columns by count (distinct ranks via index tiebreak)
    if (tid < U_) {
        int c = cnt[tid], r = 0;
        for (int j2 = 0; j2 < U_; ++j2) {
            int c2 = cnt[j2];
            r += (c2 < c || (c2 == c && j2 < tid)) ? 1 : 0;
        }
        sortedv[r] = tid;
    }
    __syncthreads();
    if (tid < 128) {
        int tot = cnt[sortedv[tid]] + cnt[sortedv[255 - tid]];
        int Lp = (tot + 3) >> 2;
        if (Lp > SLOTS) Lp = SLOTS;
        if (Lp < 1) Lp = 1;
        pairLp[tid] = Lp;
    }
    __syncthreads();
    // per main-thread metadata
    {
        int p = tid >> 2, q = tid & 3;
        int jA = sortedv[p], jB = sortedv[255 - p];
        int Lp = pairLp[p];
        int bp = cnt[jA] - q * Lp;
        bp = bp < 0 ? 0 : (bp > Lp ? Lp : bp);
        meta[tid] = (unsigned)jA | ((unsigned)jB << 8) | ((unsigned)bp << 16);
    }
    // emit compacted elements: 4 threads per pair (2 columns x 2 row-halves)
    {
        int p = tid >> 2, sub = tid & 3;
        int which = sub >> 1, half = sub & 1;
        int jA = sortedv[p], jB = sortedv[255 - p];
        int Lp = pairLp[p];
        int jcol = which ? jB : jA;
        int e = (which ? cnt[jA] : 0) + (half ? cntLo[jcol] : 0);
        for (int i = half * 128; i < half * 128 + 128; ++i) {
            if (mask[i * U_ + jcol] != 0.0f) {
                if (e < 4 * Lp) {
                    int t = (p << 2) + e / Lp;
                    int slot = e - (e / Lp) * Lp;
                    int idx = slot * NT + t;
                    float sg = sigma[i * U_ + jcol];
                    A[idx]  = -sg * LOG2E;
                    Bm[idx] = mu[i * U_ + jcol] * sg * LOG2E;
                    C[idx]  = log1pf(expf(w[i * U_ + jcol])) * erev[i * U_ + jcol];
                    I8[t * SLOTS + slot] = (unsigned char)i;
                }
                ++e;
            }
        }
    }
}

__global__ __launch_bounds__(NT) void lnn_main(
    const float* __restrict__ x,
    const float* __restrict__ input_w, const float* __restrict__ input_b,
    const float* __restrict__ s_w, const float* __restrict__ s_mu,
    const float* __restrict__ s_sigma, const float* __restrict__ s_erev,
    const float* __restrict__ s_mask,
    const float* __restrict__ gleak, const float* __restrict__ vleak,
    const float* __restrict__ cm,
    const float* __restrict__ ow, const float* __restrict__ ob,
    const float* __restrict__ Wout, const float* __restrict__ bout,
    const float* __restrict__ ws, float* __restrict__ out)
{
    __shared__ float vstage[U_];
    __shared__ float4 scr[NT];
    __shared__ float wnsL[B_][U_];
    __shared__ float wdsL[B_][U_];
    __shared__ float xinL[B_][S_];
    __shared__ float tsortAll[B_][L_];
    __shared__ int posAll[B_];
    __shared__ int unitInfo[U_];
    __shared__ float spweL[S_ * U_];
    __shared__ float soutL[M_];

    const int tid = threadIdx.x;

    const float* A  = ws;
    const float* Bm = ws + SLOTS * NT;
    const float* C  = ws + 2 * SLOTS * NT;
    const unsigned char* I8 = (const unsigned char*)(ws + 3 * SLOTS * NT);
    const unsigned* meta = (const unsigned*)(I8 + NT * SLOTS);

    // register-resident sparse params
    float pA[SLOTS], pB[SLOTS], pC[SLOTS];
    unsigned pI[SLOTS / 4];
#pragma unroll
    for (int e = 0; e < SLOTS; ++e) {
        pA[e] = A[e * NT + tid];
        pB[e] = Bm[e * NT + tid];
        pC[e] = C[e * NT + tid];
    }
    {
        const unsigned* I32 = (const unsigned*)(I8 + (size_t)tid * SLOTS);
#pragma unroll
        for (int e = 0; e < SLOTS / 4; ++e) pI[e] = I32[e];
    }
    const unsigned mt = meta[tid];
    const int bpos = (mt >> 16) & 255;
    if ((tid & 3) == 0) {
        int p = tid >> 2;
        unitInfo[mt & 255] = (p << 1);
        unitInfo[(mt >> 8) & 255] = (p << 1) | 1;
    }

    if (tid < U_) vstage[tid] = 0.0f;
    if (tid < B_ * S_) {
        int b = tid >> 5, s = tid & 31;
        xinL[b][s] = fmaf(x[(b * L_ + (L_ - 1)) * F_ + 1 + s], input_w[s], input_b[s]);
    }
    for (int k = tid; k < S_ * U_; k += NT)
        spweL[k] = log1pf(expf(s_w[k])) * s_mask[k] * s_erev[k];
    if (tid < B_ * L_) {
        int b = tid >> 4, l = tid & 15;
        float tv = x[(b * L_ + l) * F_];
        int r = 0;
        for (int m2 = 0; m2 < L_; ++m2) {
            float tm = x[(b * L_ + m2) * F_];
            r += (tm < tv || (tm == tv && m2 < l)) ? 1 : 0;
        }
        tsortAll[b][r] = tv;
        if (l == L_ - 1) posAll[b] = r;
    }
    __syncthreads();

    // sensory precompute for all batches (row l = L-1 only)
#pragma unroll
    for (int rr = 0; rr < 4; ++rr) {
        int task = tid + rr * NT;          // 2048 tasks: (b, j)
        int b = task >> 8, j = task & 255;
        float an = 0.0f, ad = 0.0f;
        for (int s = 0; s < S_; ++s) {
            float xv = xinL[b][s];
            float sg = s_sigma[s * U_ + j];
            float muv = s_mu[s * U_ + j];
            float sp_ = spweL[s * U_ + j];
            float arg = (muv - xv) * (sg * LOG2E);
            float g = __builtin_amdgcn_rcpf(1.0f + __builtin_amdgcn_exp2f(arg));
            an = fmaf(sp_, g, an);
            ad = fmaf(fabsf(sp_), g, ad);
        }
        wnsL[b][j] = an; wdsL[b][j] = ad;
    }

    // per-unit constants + reduction source pointer
    float v_j = 0.0f, vs_j = 0.0f, cmv_j = 0.0f, gl_j = 0.0f, glvl_j = 0.0f;
    const float2* sb2 = (const float2*)&scr[0];
    if (tid < U_) {
        cmv_j = log1pf(expf(cm[tid]));
        gl_j  = log1pf(expf(gleak[tid]));
        glvl_j = gl_j * vleak[tid];
        int info = unitInfo[tid];
        sb2 = (const float2*)(((const float*)&scr[(info >> 1) << 2]) + ((info & 1) << 1));
    }
    __syncthreads();

    for (int b = 0; b < B_; ++b) {
        float nbase = 0.0f, dbase = 0.0f;
        if (tid < U_) {
            nbase = glvl_j + wnsL[b][tid];
            dbase = gl_j + wdsL[b][tid];
        }
        const int pos = posAll[b];
        for (int st = 0; st < pos; ++st) {
            const float t0 = tsortAll[b][st], t1 = tsortAll[b][st + 1];
            const float dt = t1 - t0;
            float k1 = 0.0f, k2 = 0.0f, k3 = 0.0f;
#pragma unroll
            for (int stage = 0; stage < 4; ++stage) {
                // sparse masked-sigmoid accumulation (all 512 threads)
                float nT = 0.0f, dT = 0.0f, nB2 = 0.0f, dB2 = 0.0f;
#pragma unroll
                for (int e = 0; e < SLOTS; ++e) {
                    int iv = (pI[e >> 2] >> ((e & 3) * 8)) & 255;
                    float vi = vstage[iv];
                    float arg = fmaf(pA[e], vi, pB[e]);
                    float g = __builtin_amdgcn_rcpf(1.0f + __builtin_amdgcn_exp2f(arg));
                    float vn = pC[e] * g;
                    float selm = (e >= bpos) ? 1.0f : 0.0f;
                    nT += vn;
                    dT += fabsf(vn);
                    nB2 = fmaf(vn, selm, nB2);
                    dB2 = fmaf(fabsf(vn), selm, dB2);
                }
                scr[tid] = make_float4(nT - nB2, dT - dB2, nB2, dB2);
                __syncthreads();
                if (tid < U_) {
                    float2 a0 = sb2[0], a1 = sb2[2], a2 = sb2[4], a3 = sb2[6];
                    float nsum = (a0.x + a1.x) + (a2.x + a3.x);
                    float dsum = (a0.y + a1.y) + (a2.y + a3.y);
                    float tcur = (stage == 0) ? t0
                               : (stage == 1) ? fmaf(dt, 1.0f / 3.0f, t0)
                               : (stage == 2) ? fmaf(dt, 2.0f / 3.0f, t0) : t1;
                    float cmt = cmv_j * __builtin_amdgcn_rcpf(tcur + EPSF);
                    float numf = fmaf(cmt, vs_j, nbase) + nsum;
                    float denf = cmt + dbase + dsum;
                    float kk = numf * __builtin_amdgcn_rcpf(denf + EPSF) - vs_j;
                    if (stage == 0)      { k1 = kk; vs_j = fmaf(dt * (1.0f / 3.0f), kk, v_j); }
                    else if (stage == 1) { k2 = kk; vs_j = v_j + dt * (kk - k1 * (1.0f / 3.0f)); }
                    else if (stage == 2) { k3 = kk; vs_j = v_j + dt * (k1 - k2 + kk); }
                    else { v_j = fmaf(dt * 0.125f, fmaf(3.0f, k2 + k3, k1 + kk), v_j); vs_j = v_j; }
                    vstage[tid] = vs_j;
                }
                __syncthreads();
            }
        }

        // cell output: y[b] = (v[:64]*ow + ob) @ Wout + bout
        if (tid < M_) soutL[tid] = fmaf(vstage[tid], ow[tid], ob[tid]);
        __syncthreads();
        if (tid < O_) {
            float acc = bout[tid];
            for (int m2 = 0; m2 < M_; ++m2) acc = fmaf(soutL[m2], Wout[m2 * O_ + tid], acc);
            out[b * O_ + tid] = acc;
        }
        __syncthreads();
    }
}

extern "C" void kernel_launch(void* const* d_in, const int* in_sizes, int n_in,
                              void* d_out, int out_size, void* d_ws, size_t ws_size,
                              hipStream_t stream) {
    const float* x        = (const float*)d_in[0];
    const float* input_w  = (const float*)d_in[1];
    const float* input_b  = (const float*)d_in[2];
    const float* s_w      = (const float*)d_in[3];
    const float* s_mu     = (const float*)d_in[4];
    const float* s_sigma  = (const float*)d_in[5];
    const float* s_erev   = (const float*)d_in[6];
    const float* s_mask   = (const float*)d_in[7];
    const float* w        = (const float*)d_in[8];
    const float* mu       = (const float*)d_in[9];
    const float* sigma    = (const float*)d_in[10];
    const float* erev     = (const float*)d_in[11];
    const float* mask     = (const float*)d_in[12];
    const float* gleak    = (const float*)d_in[13];
    const float* vleak    = (const float*)d_in[14];
    const float* cm       = (const float*)d_in[15];
    const float* output_w = (const float*)d_in[16];
    const float* output_b = (const float*)d_in[17];
    const float* Wout     = (const float*)d_in[18];
    const float* bout     = (const float*)d_in[19];

    float* ws = (float*)d_ws;
    lnn_prep<<<1, NT, 0, stream>>>(w, mu, sigma, erev, mask, ws);
    lnn_main<<<1, NT, 0, stream>>>(x, input_w, input_b, s_w, s_mu, s_sigma, s_erev,
                                   s_mask, gleak, vleak, cm, output_w, output_b,
                                   Wout, bout, ws, (float*)d_out);
}

// Round 3
// 1131.016 us; speedup vs baseline: 1.2618x; 1.2618x over previous
//
#include <hip/hip_runtime.h>

#define U_ 256
#define B_ 8
#define L_ 16
#define F_ 33
#define S_ 32
#define M_ 64
#define O_ 8
#define SLOTS 20
#define NSEG 6
#define NT 1024
#define LOG2E 1.44269504088896340736f
#define EPSF 1e-8f

// d_ws layout (floats from base):
//   A   [SLOTS*NT] : -sigma*log2e        (slot-major: A[e*NT + t])
//   Bm  [SLOTS*NT] : mu*sigma*log2e
//   C   [SLOTS*NT] : softplus(w)*erev    (0 => padding slot)
//   I8  uint8[NT*SLOTS] : presynaptic index i, layout [t][slot]
//   metaT    uint32[NT] : jA | jB<<8 | bpos<<16   (flat chunk metadata)
//   unitMeta uint32[U_] : firstThread | span<<16

__global__ __launch_bounds__(NT) void lnn_prep(
    const float* __restrict__ w, const float* __restrict__ mu,
    const float* __restrict__ sigma, const float* __restrict__ erev,
    const float* __restrict__ mask, float* __restrict__ ws)
{
    __shared__ int cntQ[4][U_];
    __shared__ int colS[U_ + 1];

    const int tid = threadIdx.x;
    float* A  = ws;
    float* Bm = ws + SLOTS * NT;
    float* C  = ws + 2 * SLOTS * NT;
    unsigned char* I8 = (unsigned char*)(ws + 3 * SLOTS * NT);
    unsigned* metaT = (unsigned*)(I8 + NT * SLOTS);
    unsigned* unitMeta = metaT + NT;

    // zero param region (ws is poisoned 0xAA before every launch)
    for (int k = tid; k < 3 * SLOTS * NT; k += NT) ws[k] = 0.0f;
    for (int k = tid; k < NT * SLOTS / 4; k += NT) ((unsigned*)I8)[k] = 0u;

    // quarter-column nonzero counts (1024 threads = 4 quarters x 256 cols)
    const int q = tid >> 8, j = tid & 255;
    {
        int c = 0;
        for (int i = q * 64; i < q * 64 + 64; ++i)
            c += (mask[i * U_ + j] != 0.0f) ? 1 : 0;
        cntQ[q][j] = c;
    }
    __syncthreads();
    if (tid == 0) {
        int run = 0;
        for (int jj = 0; jj < U_; ++jj) {
            colS[jj] = run;
            run += cntQ[0][jj] + cntQ[1][jj] + cntQ[2][jj] + cntQ[3][jj];
        }
        colS[U_] = run;
    }
    __syncthreads();

    // emit compacted elements (column-major flat order, chunked by SLOTS)
    {
        int e = colS[j];
        for (int qq = 0; qq < q; ++qq) e += cntQ[qq][j];
        for (int i = q * 64; i < q * 64 + 64; ++i) {
            if (mask[i * U_ + j] != 0.0f) {
                int t2 = e / SLOTS;
                int slot = e - t2 * SLOTS;
                if (t2 < NT) {
                    float sg = sigma[i * U_ + j];
                    A[slot * NT + t2]  = -sg * LOG2E;
                    Bm[slot * NT + t2] = mu[i * U_ + j] * sg * LOG2E;
                    C[slot * NT + t2]  = log1pf(expf(w[i * U_ + j])) * erev[i * U_ + j];
                    I8[t2 * SLOTS + slot] = (unsigned char)i;
                }
                ++e;
            }
        }
    }

    // per-thread chunk metadata: owning column jA, boundary bpos, next col jB
    {
        int E = tid * SLOTS;
        int lo = 0, hi = U_;
        while (hi - lo > 1) { int mid = (lo + hi) >> 1; if (colS[mid] <= E) lo = mid; else hi = mid; }
        int jA = lo;
        int bp = colS[jA + 1] - E;
        bp = bp < 0 ? 0 : (bp > SLOTS ? SLOTS : bp);
        int jB = (jA + 1 > 255) ? 255 : jA + 1;
        metaT[tid] = (unsigned)jA | ((unsigned)jB << 8) | ((unsigned)bp << 16);
    }

    // per-unit reduce span
    if (tid < U_) {
        int cs = colS[tid], ce = colS[tid + 1];
        int s = cs / SLOTS;
        int span = (ce > cs) ? ((ce - 1) / SLOTS - s + 1) : 0;
        if (span > NSEG) span = NSEG;
        unitMeta[tid] = (unsigned)s | ((unsigned)span << 16);
    }
}

__global__ __launch_bounds__(NT) void lnn_main(
    const float* __restrict__ x,
    const float* __restrict__ input_w, const float* __restrict__ input_b,
    const float* __restrict__ s_w, const float* __restrict__ s_mu,
    const float* __restrict__ s_sigma, const float* __restrict__ s_erev,
    const float* __restrict__ s_mask,
    const float* __restrict__ gleak, const float* __restrict__ vleak,
    const float* __restrict__ cm,
    const float* __restrict__ ow, const float* __restrict__ ob,
    const float* __restrict__ Wout, const float* __restrict__ bout,
    const float* __restrict__ ws, float* __restrict__ out)
{
    __shared__ float vstage[U_];
    __shared__ float4 scr[NT];
    __shared__ unsigned metaTL[NT];
    __shared__ float wnsL[B_][U_];
    __shared__ float wdsL[B_][U_];
    __shared__ float xinL[B_][S_];
    __shared__ float tsortAll[B_][L_];
    __shared__ int posAll[B_];
    __shared__ float spweL[S_ * U_];
    __shared__ float soutL[M_];

    const int tid = threadIdx.x;

    const float* A  = ws;
    const float* Bm = ws + SLOTS * NT;
    const float* C  = ws + 2 * SLOTS * NT;
    const unsigned char* I8 = (const unsigned char*)(ws + 3 * SLOTS * NT);
    const unsigned* metaT = (const unsigned*)(I8 + NT * SLOTS);
    const unsigned* unitMeta = metaT + NT;

    // register-resident sparse params (60 + 5 regs — fits 128 VGPR budget)
    float pA[SLOTS], pB[SLOTS], pC[SLOTS];
    unsigned pI[SLOTS / 4];
#pragma unroll
    for (int e = 0; e < SLOTS; ++e) {
        pA[e] = A[e * NT + tid];
        pB[e] = Bm[e * NT + tid];
        pC[e] = C[e * NT + tid];
    }
    {
        const unsigned* I32 = (const unsigned*)(I8 + (size_t)tid * SLOTS);
#pragma unroll
        for (int e = 0; e < SLOTS / 4; ++e) pI[e] = I32[e];
    }
    const unsigned mt = metaT[tid];
    const int bpos = (mt >> 16) & 255;
    metaTL[tid] = mt;

    if (tid < U_) vstage[tid] = 0.0f;
    if (tid < B_ * S_) {
        int b = tid >> 5, s = tid & 31;
        xinL[b][s] = fmaf(x[(b * L_ + (L_ - 1)) * F_ + 1 + s], input_w[s], input_b[s]);
    }
    for (int k = tid; k < S_ * U_; k += NT)
        spweL[k] = log1pf(expf(s_w[k])) * s_mask[k] * s_erev[k];
    if (tid < B_ * L_) {
        int b = tid >> 4, l = tid & 15;
        float tv = x[(b * L_ + l) * F_];
        int r = 0;
        for (int m2 = 0; m2 < L_; ++m2) {
            float tm = x[(b * L_ + m2) * F_];
            r += (tm < tv || (tm == tv && m2 < l)) ? 1 : 0;
        }
        tsortAll[b][r] = tv;
        if (l == L_ - 1) posAll[b] = r;
    }
    __syncthreads();

    // sensory precompute for all batches (row l = L-1 only)
#pragma unroll
    for (int rr = 0; rr < 2; ++rr) {
        int task = tid + rr * NT;          // 2048 tasks: (b, j)
        int b = task >> 8, jj = task & 255;
        float an = 0.0f, ad = 0.0f;
        for (int s = 0; s < S_; ++s) {
            float xv = xinL[b][s];
            float sg = s_sigma[s * U_ + jj];
            float muv = s_mu[s * U_ + jj];
            float sp_ = spweL[s * U_ + jj];
            float arg = (muv - xv) * (sg * LOG2E);
            float g = __builtin_amdgcn_rcpf(1.0f + __builtin_amdgcn_exp2f(arg));
            an = fmaf(sp_, g, an);
            ad = fmaf(fabsf(sp_), g, ad);
        }
        wnsL[b][jj] = an; wdsL[b][jj] = ad;
    }

    // per-unit constants + reduce span
    float v_j = 0.0f, vs_j = 0.0f, cmv_j = 0.0f, gl_j = 0.0f, glvl_j = 0.0f;
    int sU = 0, spanU = 0;
    if (tid < U_) {
        cmv_j = log1pf(expf(cm[tid]));
        gl_j  = log1pf(expf(gleak[tid]));
        glvl_j = gl_j * vleak[tid];
        unsigned um = unitMeta[tid];
        sU = um & 0xFFFF;
        spanU = um >> 16;
    }
    __syncthreads();

    for (int b = 0; b < B_; ++b) {
        float nbase = 0.0f, dbase = 0.0f;
        if (tid < U_) {
            nbase = glvl_j + wnsL[b][tid];
            dbase = gl_j + wdsL[b][tid];
        }
        const int pos = posAll[b];
        for (int st = 0; st < pos; ++st) {
            const float t0 = tsortAll[b][st], t1 = tsortAll[b][st + 1];
            const float dt = t1 - t0;
            float k1 = 0.0f, k2 = 0.0f, k3 = 0.0f;
#pragma unroll
            for (int stage = 0; stage < 4; ++stage) {
                // prefetch all gathers, then pure-VALU accumulation
                float viR[SLOTS];
#pragma unroll
                for (int e = 0; e < SLOTS; ++e)
                    viR[e] = vstage[(pI[e >> 2] >> ((e & 3) * 8)) & 255];
                float nT = 0.0f, dT = 0.0f, nB2 = 0.0f, dB2 = 0.0f;
#pragma unroll
                for (int e = 0; e < SLOTS; ++e) {
                    float arg = fmaf(pA[e], viR[e], pB[e]);
                    float g = __builtin_amdgcn_rcpf(1.0f + __builtin_amdgcn_exp2f(arg));
                    float vn = pC[e] * g;
                    float selm = (e >= bpos) ? 1.0f : 0.0f;
                    nT += vn;
                    dT += fabsf(vn);
                    nB2 = fmaf(vn, selm, nB2);
                    dB2 = fmaf(fabsf(vn), selm, dB2);
                }
                scr[tid] = make_float4(nT - nB2, dT - dB2, nB2, dB2);
                __syncthreads();
                if (tid < U_) {
                    float nsum = 0.0f, dsum = 0.0f;
#pragma unroll
                    for (int k = 0; k < NSEG; ++k) {
                        int t2 = sU + k;
                        unsigned m2 = metaTL[t2];
                        float4 a = scr[t2];
                        bool valid = k < spanU;
                        bool isA = (m2 & 255u) == (unsigned)tid;
                        bool selA = valid && isA;
                        bool selB = valid && !isA && (((m2 >> 8) & 255u) == (unsigned)tid);
                        nsum += selA ? a.x : (selB ? a.z : 0.0f);
                        dsum += selA ? a.y : (selB ? a.w : 0.0f);
                    }
                    float tcur = (stage == 0) ? t0
                               : (stage == 1) ? fmaf(dt, 1.0f / 3.0f, t0)
                               : (stage == 2) ? fmaf(dt, 2.0f / 3.0f, t0) : t1;
                    float cmt = cmv_j * __builtin_amdgcn_rcpf(tcur + EPSF);
                    float numf = fmaf(cmt, vs_j, nbase) + nsum;
                    float denf = cmt + dbase + dsum;
                    float kk = numf * __builtin_amdgcn_rcpf(denf + EPSF) - vs_j;
                    if (stage == 0)      { k1 = kk; vs_j = fmaf(dt * (1.0f / 3.0f), kk, v_j); }
                    else if (stage == 1) { k2 = kk; vs_j = v_j + dt * (kk - k1 * (1.0f / 3.0f)); }
                    else if (stage == 2) { k3 = kk; vs_j = v_j + dt * (k1 - k2 + kk); }
                    else { v_j = fmaf(dt * 0.125f, fmaf(3.0f, k2 + k3, k1 + kk), v_j); vs_j = v_j; }
                    vstage[tid] = vs_j;
                }
                __syncthreads();
            }
        }

        // cell output: y[b] = (v[:64]*ow + ob) @ Wout + bout
        if (tid < M_) soutL[tid] = fmaf(vstage[tid], ow[tid], ob[tid]);
        __syncthreads();
        if (tid < O_) {
            float acc = bout[tid];
            for (int m2 = 0; m2 < M_; ++m2) acc = fmaf(soutL[m2], Wout[m2 * O_ + tid], acc);
            out[b * O_ + tid] = acc;
        }
        __syncthreads();
    }
}

extern "C" void kernel_launch(void* const* d_in, const int* in_sizes, int n_in,
                              void* d_out, int out_size, void* d_ws, size_t ws_size,
                              hipStream_t stream) {
    const float* x        = (const float*)d_in[0];
    const float* input_w  = (const float*)d_in[1];
    const float* input_b  = (const float*)d_in[2];
    const float* s_w      = (const float*)d_in[3];
    const float* s_mu     = (const float*)d_in[4];
    const float* s_sigma  = (const float*)d_in[5];
    const float* s_erev   = (const float*)d_in[6];
    const float* s_mask   = (const float*)d_in[7];
    const float* w        = (const float*)d_in[8];
    const float* mu       = (const float*)d_in[9];
    const float* sigma    = (const float*)d_in[10];
    const float* erev     = (const float*)d_in[11];
    const float* mask     = (const float*)d_in[12];
    const float* gleak    = (const float*)d_in[13];
    const float* vleak    = (const float*)d_in[14];
    const float* cm       = (const float*)d_in[15];
    const float* output_w = (const float*)d_in[16];
    const float* output_b = (const float*)d_in[17];
    const float* Wout     = (const float*)d_in[18];
    const float* bout     = (const float*)d_in[19];

    float* ws = (float*)d_ws;
    lnn_prep<<<1, NT, 0, stream>>>(w, mu, sigma, erev, mask, ws);
    lnn_main<<<1, NT, 0, stream>>>(x, input_w, input_b, s_w, s_mu, s_sigma, s_erev,
                                   s_mask, gleak, vleak, cm, output_w, output_b,
                                   Wout, bout, ws, (float*)d_out);
}

// Round 12
// 1116.887 us; speedup vs baseline: 1.2777x; 1.0127x over previous
//
#include <hip/hip_runtime.h>

#define U_ 256
#define B_ 8
#define L_ 16
#define F_ 33
#define S_ 32
#define M_ 64
#define O_ 8
#define SLOTS 20
#define NSEG 6
#define NT 1024
#define LOG2E 1.44269504088896340736f
#define EPSF 1e-8f

// d_ws layout (floats from base):
//   A   [SLOTS*NT] : -sigma*log2e        (slot-major: A[e*NT + t])
//   Bm  [SLOTS*NT] : mu*sigma*log2e
//   C   [SLOTS*NT] : softplus(w)*erev    (0 => padding slot)
//   I8  uint8[NT*SLOTS] : presynaptic index i, layout [t][slot]
//   metaT    uint32[NT] : jA | jB<<8 | bpos<<16   (flat chunk metadata)
//   unitMeta uint32[U_] : firstThread | span<<16
//
// NOTE (round-8 lesson): the reference lax.scan carries new_state ACROSS
// BATCHES (scan axis = B). The 8 batches form ONE sequential chain — they
// cannot be parallelized across blocks. Single block, b-loop with v carry.

__global__ __launch_bounds__(NT) void lnn_prep(
    const float* __restrict__ w, const float* __restrict__ mu,
    const float* __restrict__ sigma, const float* __restrict__ erev,
    const float* __restrict__ mask, float* __restrict__ ws)
{
    __shared__ int cntQ[4][U_];
    __shared__ int colS[U_ + 1];

    const int tid = threadIdx.x;
    float* A  = ws;
    float* Bm = ws + SLOTS * NT;
    float* C  = ws + 2 * SLOTS * NT;
    unsigned char* I8 = (unsigned char*)(ws + 3 * SLOTS * NT);
    unsigned* metaT = (unsigned*)(I8 + NT * SLOTS);
    unsigned* unitMeta = metaT + NT;

    // zero param region (ws is poisoned 0xAA before every launch)
    for (int k = tid; k < 3 * SLOTS * NT; k += NT) ws[k] = 0.0f;
    for (int k = tid; k < NT * SLOTS / 4; k += NT) ((unsigned*)I8)[k] = 0u;

    // quarter-column nonzero counts (1024 threads = 4 quarters x 256 cols)
    const int q = tid >> 8, j = tid & 255;
    {
        int c = 0;
        for (int i = q * 64; i < q * 64 + 64; ++i)
            c += (mask[i * U_ + j] != 0.0f) ? 1 : 0;
        cntQ[q][j] = c;
    }
    __syncthreads();
    // parallel prefix: colS[k] = sum of column counts for cols < k
    if (tid < U_) colS[tid + 1] = cntQ[0][tid] + cntQ[1][tid] + cntQ[2][tid] + cntQ[3][tid];
    if (tid == 0) colS[0] = 0;
    __syncthreads();
    for (int off = 1; off < U_; off <<= 1) {
        int v2 = 0;
        if (tid < U_) {
            v2 = colS[tid + 1];
            if (tid + 1 > off) v2 += colS[tid + 1 - off];
        }
        __syncthreads();
        if (tid < U_) colS[tid + 1] = v2;
        __syncthreads();
    }

    // emit compacted elements (column-major flat order, chunked by SLOTS)
    {
        int e = colS[j];
        for (int qq = 0; qq < q; ++qq) e += cntQ[qq][j];
        for (int i = q * 64; i < q * 64 + 64; ++i) {
            if (mask[i * U_ + j] != 0.0f) {
                int t2 = e / SLOTS;
                int slot = e - t2 * SLOTS;
                if (t2 < NT) {
                    float sg = sigma[i * U_ + j];
                    A[slot * NT + t2]  = -sg * LOG2E;
                    Bm[slot * NT + t2] = mu[i * U_ + j] * sg * LOG2E;
                    C[slot * NT + t2]  = log1pf(expf(w[i * U_ + j])) * erev[i * U_ + j];
                    I8[t2 * SLOTS + slot] = (unsigned char)i;
                }
                ++e;
            }
        }
    }

    // per-thread chunk metadata: owning column jA, boundary bpos, next col jB
    {
        int E = tid * SLOTS;
        int lo = 0, hi = U_;
        while (hi - lo > 1) { int mid = (lo + hi) >> 1; if (colS[mid] <= E) lo = mid; else hi = mid; }
        int jA = lo;
        int bp = colS[jA + 1] - E;
        bp = bp < 0 ? 0 : (bp > SLOTS ? SLOTS : bp);
        int jB = (jA + 1 > 255) ? 255 : jA + 1;
        metaT[tid] = (unsigned)jA | ((unsigned)jB << 8) | ((unsigned)bp << 16);
    }

    // per-unit reduce span
    if (tid < U_) {
        int cs = colS[tid], ce = colS[tid + 1];
        int s = cs / SLOTS;
        int span = (ce > cs) ? ((ce - 1) / SLOTS - s + 1) : 0;
        if (span > NSEG) span = NSEG;
        unitMeta[tid] = (unsigned)s | ((unsigned)span << 16);
    }
}

__global__ __launch_bounds__(NT, 4) void lnn_main(
    const float* __restrict__ x,
    const float* __restrict__ input_w, const float* __restrict__ input_b,
    const float* __restrict__ s_w, const float* __restrict__ s_mu,
    const float* __restrict__ s_sigma, const float* __restrict__ s_erev,
    const float* __restrict__ s_mask,
    const float* __restrict__ gleak, const float* __restrict__ vleak,
    const float* __restrict__ cm,
    const float* __restrict__ ow, const float* __restrict__ ob,
    const float* __restrict__ Wout, const float* __restrict__ bout,
    const float* __restrict__ ws, float* __restrict__ out)
{
    __shared__ float vstage[U_];
    __shared__ float4 scr[NT];
    __shared__ unsigned metaTL[NT];
    __shared__ float wnsL[B_][U_];
    __shared__ float wdsL[B_][U_];
    __shared__ float xinL[B_][S_];
    __shared__ float tsortAll[B_][L_];
    __shared__ int posAll[B_];
    __shared__ float spweL[S_ * U_];
    __shared__ float soutL[M_];

    const int tid = threadIdx.x;

    const float* A  = ws;
    const float* Bm = ws + SLOTS * NT;
    const float* C  = ws + 2 * SLOTS * NT;
    const unsigned char* I8 = (const unsigned char*)(ws + 3 * SLOTS * NT);
    const unsigned* metaT = (const unsigned*)(I8 + NT * SLOTS);
    const unsigned* unitMeta = metaT + NT;

    // register-resident sparse params
    float pA[SLOTS], pB[SLOTS], pC[SLOTS];
    unsigned pI[SLOTS / 4];
#pragma unroll
    for (int e = 0; e < SLOTS; ++e) {
        pA[e] = A[e * NT + tid];
        pB[e] = Bm[e * NT + tid];
        pC[e] = C[e * NT + tid];
    }
    {
        const unsigned* I32 = (const unsigned*)(I8 + (size_t)tid * SLOTS);
#pragma unroll
        for (int e = 0; e < SLOTS / 4; ++e) pI[e] = I32[e];
    }
    const unsigned mt = metaT[tid];
    const int bpos = (mt >> 16) & 255;
    metaTL[tid] = mt;

    if (tid < U_) vstage[tid] = 0.0f;
    if (tid < B_ * S_) {
        int b = tid >> 5, s = tid & 31;
        xinL[b][s] = fmaf(x[(b * L_ + (L_ - 1)) * F_ + 1 + s], input_w[s], input_b[s]);
    }
    for (int k = tid; k < S_ * U_; k += NT)
        spweL[k] = log1pf(expf(s_w[k])) * s_mask[k] * s_erev[k];
    if (tid < B_ * L_) {
        int b = tid >> 4, l = tid & 15;
        float tv = x[(b * L_ + l) * F_];
        int r = 0;
        for (int m2 = 0; m2 < L_; ++m2) {
            float tm = x[(b * L_ + m2) * F_];
            r += (tm < tv || (tm == tv && m2 < l)) ? 1 : 0;
        }
        tsortAll[b][r] = tv;
        if (l == L_ - 1) posAll[b] = r;
    }
    __syncthreads();

    // sensory precompute for all batches (row l = L-1 only)
#pragma unroll
    for (int rr = 0; rr < 2; ++rr) {
        int task = tid + rr * NT;          // 2048 tasks: (b, j)
        int b = task >> 8, jj = task & 255;
        float an = 0.0f, ad = 0.0f;
        for (int s = 0; s < S_; ++s) {
            float xv = xinL[b][s];
            float sg = s_sigma[s * U_ + jj];
            float muv = s_mu[s * U_ + jj];
            float sp_ = spweL[s * U_ + jj];
            float arg = (muv - xv) * (sg * LOG2E);
            float g = __builtin_amdgcn_rcpf(1.0f + __builtin_amdgcn_exp2f(arg));
            an = fmaf(sp_, g, an);
            ad = fmaf(fabsf(sp_), g, ad);
        }
        wnsL[b][jj] = an; wdsL[b][jj] = ad;
    }

    // per-unit constants + reduce span
    float v_j = 0.0f, vs_j = 0.0f, cmv_j = 0.0f, gl_j = 0.0f, glvl_j = 0.0f;
    int sU = 0, spanU = 0;
    if (tid < U_) {
        cmv_j = log1pf(expf(cm[tid]));
        gl_j  = log1pf(expf(gleak[tid]));
        glvl_j = gl_j * vleak[tid];
        unsigned um = unitMeta[tid];
        sU = um & 0xFFFF;
        spanU = um >> 16;
    }
    __syncthreads();

    // pin params in registers: loads complete here and the values cannot be
    // rematerialized as per-stage L2 re-loads inside the RK loop (round-3
    // pathology: VGPR_Count=64 meant the 65-reg param set was re-fetched
    // from memory every stage)
#pragma unroll
    for (int e = 0; e < SLOTS; ++e)
        asm volatile("" : "+v"(pA[e]), "+v"(pB[e]), "+v"(pC[e]));
#pragma unroll
    for (int kp = 0; kp < SLOTS / 4; ++kp)
        asm volatile("" : "+v"(pI[kp]));

    for (int b = 0; b < B_; ++b) {
        float nbase = 0.0f, dbase = 0.0f;
        if (tid < U_) {
            nbase = glvl_j + wnsL[b][tid];
            dbase = gl_j + wdsL[b][tid];
        }
        const int pos = posAll[b];
        for (int st = 0; st < pos; ++st) {
            const float t0 = tsortAll[b][st], t1 = tsortAll[b][st + 1];
            const float dt = t1 - t0;
            float k1 = 0.0f, k2 = 0.0f, k3 = 0.0f;
#pragma unroll
            for (int stage = 0; stage < 4; ++stage) {
                // prefetch all gathers, then pure-VALU accumulation
                float viR[SLOTS];
#pragma unroll
                for (int e = 0; e < SLOTS; ++e)
                    viR[e] = vstage[(pI[e >> 2] >> ((e & 3) * 8)) & 255];
                float nT = 0.0f, dT = 0.0f, nB2 = 0.0f, dB2 = 0.0f;
#pragma unroll
                for (int e = 0; e < SLOTS; ++e) {
                    float arg = fmaf(pA[e], viR[e], pB[e]);
                    float gg = __builtin_amdgcn_rcpf(1.0f + __builtin_amdgcn_exp2f(arg));
                    float vn = pC[e] * gg;
                    float selm = (e >= bpos) ? 1.0f : 0.0f;
                    nT += vn;
                    dT += fabsf(vn);
                    nB2 = fmaf(vn, selm, nB2);
                    dB2 = fmaf(fabsf(vn), selm, dB2);
                }
                scr[tid] = make_float4(nT - nB2, dT - dB2, nB2, dB2);
                __syncthreads();
                if (tid < U_) {
                    float nsum = 0.0f, dsum = 0.0f;
#pragma unroll
                    for (int k = 0; k < NSEG; ++k) {
                        int t2 = sU + k;
                        unsigned m2 = metaTL[t2];
                        float4 a = scr[t2];
                        bool valid = k < spanU;
                        bool isA = (m2 & 255u) == (unsigned)tid;
                        bool selA = valid && isA;
                        bool selB = valid && !isA && (((m2 >> 8) & 255u) == (unsigned)tid);
                        nsum += selA ? a.x : (selB ? a.z : 0.0f);
                        dsum += selA ? a.y : (selB ? a.w : 0.0f);
                    }
                    float tcur = (stage == 0) ? t0
                               : (stage == 1) ? fmaf(dt, 1.0f / 3.0f, t0)
                               : (stage == 2) ? fmaf(dt, 2.0f / 3.0f, t0) : t1;
                    float cmt = cmv_j * __builtin_amdgcn_rcpf(tcur + EPSF);
                    float numf = fmaf(cmt, vs_j, nbase) + nsum;
                    float denf = cmt + dbase + dsum;
                    float kk = numf * __builtin_amdgcn_rcpf(denf + EPSF) - vs_j;
                    if (stage == 0)      { k1 = kk; vs_j = fmaf(dt * (1.0f / 3.0f), kk, v_j); }
                    else if (stage == 1) { k2 = kk; vs_j = v_j + dt * (kk - k1 * (1.0f / 3.0f)); }
                    else if (stage == 2) { k3 = kk; vs_j = v_j + dt * (k1 - k2 + kk); }
                    else { v_j = fmaf(dt * 0.125f, fmaf(3.0f, k2 + k3, k1 + kk), v_j); vs_j = v_j; }
                    vstage[tid] = vs_j;
                }
                __syncthreads();
            }
        }

        // cell output: y[b] = (v[:64]*ow + ob) @ Wout + bout
        if (tid < M_) soutL[tid] = fmaf(vstage[tid], ow[tid], ob[tid]);
        __syncthreads();
        if (tid < O_) {
            float acc = bout[tid];
            for (int m2 = 0; m2 < M_; ++m2) acc = fmaf(soutL[m2], Wout[m2 * O_ + tid], acc);
            out[b * O_ + tid] = acc;
        }
        __syncthreads();
    }
}

extern "C" void kernel_launch(void* const* d_in, const int* in_sizes, int n_in,
                              void* d_out, int out_size, void* d_ws, size_t ws_size,
                              hipStream_t stream) {
    const float* x        = (const float*)d_in[0];
    const float* input_w  = (const float*)d_in[1];
    const float* input_b  = (const float*)d_in[2];
    const float* s_w      = (const float*)d_in[3];
    const float* s_mu     = (const float*)d_in[4];
    const float* s_sigma  = (const float*)d_in[5];
    const float* s_erev   = (const float*)d_in[6];
    const float* s_mask   = (const float*)d_in[7];
    const float* w        = (const float*)d_in[8];
    const float* mu       = (const float*)d_in[9];
    const float* sigma    = (const float*)d_in[10];
    const float* erev     = (const float*)d_in[11];
    const float* mask     = (const float*)d_in[12];
    const float* gleak    = (const float*)d_in[13];
    const float* vleak    = (const float*)d_in[14];
    const float* cm       = (const float*)d_in[15];
    const float* output_w = (const float*)d_in[16];
    const float* output_b = (const float*)d_in[17];
    const float* Wout     = (const float*)d_in[18];
    const float* bout     = (const float*)d_in[19];

    float* ws = (float*)d_ws;
    lnn_prep<<<1, NT, 0, stream>>>(w, mu, sigma, erev, mask, ws);
    lnn_main<<<1, NT, 0, stream>>>(x, input_w, input_b, s_w, s_mu, s_sigma, s_erev,
                                   s_mask, gleak, vleak, cm, output_w, output_b,
                                   Wout, bout, ws, (float*)d_out);
}